// Round 2
// baseline (689.168 us; speedup 1.0000x reference)
//
#include <hip/hip_runtime.h>
#include <cstddef>
#include <cstdint>

#define B 256
#define N 2048
#define DH 128
#define DG 256
#define HID 256
#define SPLITS 8
#define CHUNK (N / SPLITS)  // 256 rows per block
#define SCALE 0.08838834764831845f
#define LN_EPS 1e-5f

// ---------- helpers ----------

__device__ __forceinline__ float artanh_clip(float a) {
  // a >= 0; reference clips to [-1+1e-5, 1-1e-5]; a is a norm so only the top matters
  a = fminf(a, 1.0f - 1e-5f);
  return 0.5f * __logf((1.0f + a) / (1.0f - a));
}

// logmap0 per-row scale: artanh(clip(max(n,1e-7))) / max(n,1e-7)
__device__ __forceinline__ float logmap_scale(float n2) {
  float nc = fmaxf(sqrtf(n2), 1e-7f);
  return artanh_clip(nc) / nc;
}

__device__ __forceinline__ float dotN(const float* __restrict__ wrow,
                                      const float* __restrict__ x, int n4) {
  const float4* a = (const float4*)wrow;
  const float4* bx = (const float4*)x;
  float s = 0.f;
  for (int j = 0; j < n4; ++j) {
    float4 u = a[j], v = bx[j];
    s += u.x * v.x + u.y * v.y + u.z * v.z + u.w * v.w;
  }
  return s;
}

// block reduction over 128 threads (2 waves)
__device__ __forceinline__ float blockSum128(float v, float* s_red) {
#pragma unroll
  for (int msk = 1; msk < 64; msk <<= 1) v += __shfl_xor(v, msk);
  if ((threadIdx.x & 63) == 0) s_red[threadIdx.x >> 6] = v;
  __syncthreads();
  float r = s_red[0] + s_red[1];
  __syncthreads();
  return r;
}

// merge the SPLITS per-block online-softmax partials for batch b, element tid
__device__ __forceinline__ float combine_partials(const float* __restrict__ partials,
                                                  int b, int tid) {
  const float* pb = partials + (size_t)b * SPLITS * (DH + 2);
  float M = -INFINITY;
#pragma unroll
  for (int s = 0; s < SPLITS; ++s) M = fmaxf(M, pb[s * (DH + 2) + DH]);
  float L = 0.f, a = 0.f;
#pragma unroll
  for (int s = 0; s < SPLITS; ++s) {
    float e = __expf(pb[s * (DH + 2) + DH] - M);
    L += pb[s * (DH + 2) + DH + 1] * e;
    a += pb[s * (DH + 2) + tid] * e;
  }
  return a / L;
}

// ---------- kernel 0: pooled-attention query  qvec = pool_wk_w^T (pool_wq_w (seed_g_w rho + b)) ----------

__global__ void setup_pool_query(const float* __restrict__ rho,
                                 const float* __restrict__ seed_g_w,
                                 const float* __restrict__ seed_g_b,
                                 const float* __restrict__ pool_wq_w,
                                 const float* __restrict__ pool_wk_w,
                                 float* __restrict__ q_seed,
                                 float* __restrict__ qvec) {
  const int b = blockIdx.x, tid = threadIdx.x;
  __shared__ __align__(16) float s_rho[DG];
  __shared__ __align__(16) float s_qs[DH];
  __shared__ __align__(16) float s_qk[DH];
  s_rho[tid] = rho[b * DG + tid];
  s_rho[tid + DH] = rho[b * DG + tid + DH];
  __syncthreads();
  float qs = seed_g_b[tid] + dotN(seed_g_w + (size_t)tid * DG, s_rho, DG / 4);
  q_seed[b * DH + tid] = qs;
  s_qs[tid] = qs;
  __syncthreads();
  float qk = dotN(pool_wq_w + (size_t)tid * DH, s_qs, DH / 4);
  s_qk[tid] = qk;
  __syncthreads();
  float qp = 0.f;
  for (int i = 0; i < DH; ++i) qp += pool_wk_w[i * DH + tid] * s_qk[i];
  qvec[b * DH + tid] = qp;
}

// ---------- attention pass: online softmax over n of (qvec . logmap0(demo[b,n])) * SCALE,
//            accumulating  acc = sum_n p_n * logmap0(demo[b,n])  (split over SPLITS chunks) ----------

__global__ __launch_bounds__(256, 8) void attn_pass(const float* __restrict__ demo,
                                                    const float* __restrict__ qvec,
                                                    float* __restrict__ partials) {
  const int blk = blockIdx.x;
  const int b = blk >> 3;       // SPLITS == 8
  const int s = blk & 7;
  const int tid = threadIdx.x;
  const int w = tid >> 6;       // wave id 0..3
  const int lane = tid & 63;
  const int il = lane & 31;
  const int half = lane >> 5;   // 2 rows per wave iteration (half-wave each)

  const float4 qv = *(const float4*)(qvec + b * DH + ((lane * 4) & 127));
  const float* base = demo + ((size_t)b * N + (size_t)s * CHUNK) * DH;

  float m = -INFINITY, l = 0.0f;
  float4 acc = make_float4(0.f, 0.f, 0.f, 0.f);

  for (int k = 0; k < CHUNK / 8; ++k) {
    const int n0 = k * 8 + w * 2;  // this wave's row pair (block covers 8 consecutive rows/iter)
    float4 x = *(const float4*)(base + (size_t)n0 * DH + lane * 4);
    float pn = x.x * x.x + x.y * x.y + x.z * x.z + x.w * x.w;
    float pd = qv.x * x.x + qv.y * x.y + qv.z * x.z + qv.w * x.w;
#pragma unroll
    for (int msk = 1; msk < 32; msk <<= 1) {
      pn += __shfl_xor(pn, msk);
      pd += __shfl_xor(pd, msk);
    }
    float on = __shfl_xor(pn, 32);
    float od = __shfl_xor(pd, 32);
    float n2A = half ? on : pn, dA = half ? od : pd;
    float n2B = half ? pn : on, dB = half ? pd : od;
    float tsA = logmap_scale(n2A);
    float tsB = logmap_scale(n2B);
    float sA = dA * tsA * SCALE;
    float sB = dB * tsB * SCALE;
    float mNew = fmaxf(m, fmaxf(sA, sB));
    float alpha = __expf(m - mNew);  // m=-inf first iter -> alpha=0
    float pA = __expf(sA - mNew);
    float pB = __expf(sB - mNew);
    l = l * alpha + pA + pB;
    float coeff = half ? pB * tsB : pA * tsA;  // p * logmap-scale (t = ts*x)
    acc.x = acc.x * alpha + coeff * x.x;
    acc.y = acc.y * alpha + coeff * x.y;
    acc.z = acc.z * alpha + coeff * x.z;
    acc.w = acc.w * alpha + coeff * x.w;
    m = mNew;
  }
  // fold the two half-wave accumulators (same m/l reference)
  acc.x += __shfl_xor(acc.x, 32);
  acc.y += __shfl_xor(acc.y, 32);
  acc.z += __shfl_xor(acc.z, 32);
  acc.w += __shfl_xor(acc.w, 32);

  __shared__ __align__(16) float s_acc[4][DH];
  __shared__ float s_m[4], s_l[4];
  if (half == 0) *(float4*)&s_acc[w][il * 4] = acc;
  if (lane == 0) {
    s_m[w] = m;
    s_l[w] = l;
  }
  __syncthreads();
  if (tid < DH) {
    float M = fmaxf(fmaxf(s_m[0], s_m[1]), fmaxf(s_m[2], s_m[3]));
    float e0 = __expf(s_m[0] - M), e1 = __expf(s_m[1] - M);
    float e2 = __expf(s_m[2] - M), e3 = __expf(s_m[3] - M);
    float L = s_l[0] * e0 + s_l[1] * e1 + s_l[2] * e2 + s_l[3] * e3;
    float a = s_acc[0][tid] * e0 + s_acc[1][tid] * e1 + s_acc[2][tid] * e2 + s_acc[3][tid] * e3;
    float* p = partials + (size_t)blk * (DH + 2);
    p[tid] = a;
    if (tid == 0) {
      p[DH] = M;
      p[DH + 1] = L;
    }
  }
}

// ---------- transition after pool pass: u = expmap0(q_seed + seed_d_w (pool_wv_w w0));
//            then u_tan = LN(logmap0(u)), q, and next query qvec = kv_w^T q ----------

__global__ void trans_pool(const float* __restrict__ partials,
                           const float* __restrict__ q_seed,
                           const float* __restrict__ rho,
                           const float* __restrict__ pool_wv_w,
                           const float* __restrict__ seed_d_w,
                           const float* __restrict__ q_u_w,
                           const float* __restrict__ q_g_w,
                           const float* __restrict__ q_g_b,
                           const float* __restrict__ kv_w,
                           const float* __restrict__ ln_g,
                           const float* __restrict__ ln_b,
                           float* __restrict__ u_tan_out,
                           float* __restrict__ qvec_out) {
  const int b = blockIdx.x, tid = threadIdx.x;
  __shared__ __align__(16) float s_a[DH];
  __shared__ __align__(16) float s_b[DH];
  __shared__ __align__(16) float s_rho[DG];
  __shared__ float s_red[2];

  float w0 = combine_partials(partials, b, tid);
  s_a[tid] = w0;
  s_rho[tid] = rho[b * DG + tid];
  s_rho[tid + DH] = rho[b * DG + tid + DH];
  __syncthreads();
  float pooled = dotN(pool_wv_w + (size_t)tid * DH, s_a, DH / 4);
  s_b[tid] = pooled;
  __syncthreads();
  float v = q_seed[b * DH + tid] + dotN(seed_d_w + (size_t)tid * DH, s_b, DH / 4);
  // expmap0
  float n2 = blockSum128(v * v, s_red);
  float nc = fmaxf(sqrtf(n2), 1e-7f);
  float u = v * (tanhf(nc) / nc);
  // logmap0
  float nu2 = blockSum128(u * u, s_red);
  float nuc = fmaxf(sqrtf(nu2), 1e-7f);
  float ut = u * (artanh_clip(nuc) / nuc);
  // LayerNorm — the reference REASSIGNS u_tan to the LN'd value; downstream
  // expmap0(u_tan + upd) uses the post-LN tangent. Store y, not ut.
  float mu = blockSum128(ut, s_red) * (1.0f / DH);
  float d = ut - mu;
  float var = blockSum128(d * d, s_red) * (1.0f / DH);
  float y = d * rsqrtf(var + LN_EPS) * ln_g[tid] + ln_b[tid];
  u_tan_out[b * DH + tid] = y;
  s_a[tid] = y;
  __syncthreads();
  float q = q_g_b[tid] + dotN(q_u_w + (size_t)tid * DH, s_a, DH / 4) +
            dotN(q_g_w + (size_t)tid * DG, s_rho, DG / 4);
  s_b[tid] = q;
  __syncthreads();
  float qp = 0.f;
  for (int i = 0; i < DH; ++i) qp += kv_w[i * DH + tid] * s_b[i];
  qvec_out[b * DH + tid] = qp;
}

// ---------- loop-iteration transition: delta = kv_w w; MLP; u = expmap0(u_tan_in + upd);
//            if !final: next u_tan (post-LN) / q / qvec; else write output ----------

__global__ void trans_iter(const float* __restrict__ partials,
                           const float* __restrict__ u_tan_in,
                           const float* __restrict__ rho,
                           const float* __restrict__ kv_w,
                           const float* __restrict__ mlp_w1,
                           const float* __restrict__ mlp_b1,
                           const float* __restrict__ mlp_w2,
                           const float* __restrict__ mlp_b2,
                           const float* __restrict__ q_u_w,
                           const float* __restrict__ q_g_w,
                           const float* __restrict__ q_g_b,
                           const float* __restrict__ ln_g,
                           const float* __restrict__ ln_b,
                           float* __restrict__ u_tan_out,
                           float* __restrict__ qvec_out,
                           float* __restrict__ out, int is_final) {
  const int b = blockIdx.x, tid = threadIdx.x;
  __shared__ __align__(16) float s_a[DH];
  __shared__ __align__(16) float s_b[DH];
  __shared__ __align__(16) float s_h[HID];
  __shared__ __align__(16) float s_rho[DG];
  __shared__ float s_red[2];

  float wv = combine_partials(partials, b, tid);
  s_a[tid] = wv;
  s_rho[tid] = rho[b * DG + tid];
  s_rho[tid + DH] = rho[b * DG + tid + DH];
  __syncthreads();
  float delta = dotN(kv_w + (size_t)tid * DH, s_a, DH / 4);
  s_b[tid] = delta;
  __syncthreads();
  float h0 = mlp_b1[tid] + dotN(mlp_w1 + (size_t)tid * DH, s_b, DH / 4);
  float h1 = mlp_b1[tid + DH] + dotN(mlp_w1 + (size_t)(tid + DH) * DH, s_b, DH / 4);
  s_h[tid] = 0.5f * h0 * (1.0f + erff(h0 * 0.70710678118654752f));
  s_h[tid + DH] = 0.5f * h1 * (1.0f + erff(h1 * 0.70710678118654752f));
  __syncthreads();
  float upd = mlp_b2[tid] + dotN(mlp_w2 + (size_t)tid * HID, s_h, HID / 4);
  float v = u_tan_in[b * DH + tid] + upd;
  // expmap0
  float n2 = blockSum128(v * v, s_red);
  float nc = fmaxf(sqrtf(n2), 1e-7f);
  float u = v * (tanhf(nc) / nc);
  if (is_final) {
    out[b * DH + tid] = u;
    return;
  }
  // logmap0
  float nu2 = blockSum128(u * u, s_red);
  float nuc = fmaxf(sqrtf(nu2), 1e-7f);
  float ut = u * (artanh_clip(nuc) / nuc);
  // LayerNorm — store POST-LN tangent (reference reassigns u_tan)
  float mu = blockSum128(ut, s_red) * (1.0f / DH);
  float d = ut - mu;
  float var = blockSum128(d * d, s_red) * (1.0f / DH);
  float y = d * rsqrtf(var + LN_EPS) * ln_g[tid] + ln_b[tid];
  u_tan_out[b * DH + tid] = y;
  s_a[tid] = y;
  __syncthreads();
  float q = q_g_b[tid] + dotN(q_u_w + (size_t)tid * DH, s_a, DH / 4) +
            dotN(q_g_w + (size_t)tid * DG, s_rho, DG / 4);
  s_b[tid] = q;
  __syncthreads();
  float qp = 0.f;
  for (int i = 0; i < DH; ++i) qp += kv_w[i * DH + tid] * s_b[i];
  qvec_out[b * DH + tid] = qp;
}

// ---------- launch ----------

extern "C" void kernel_launch(void* const* d_in, const int* in_sizes, int n_in,
                              void* d_out, int out_size, void* d_ws, size_t ws_size,
                              hipStream_t stream) {
  const float* demo      = (const float*)d_in[0];
  const float* rho       = (const float*)d_in[1];
  const float* seed_g_w  = (const float*)d_in[2];
  const float* seed_g_b  = (const float*)d_in[3];
  const float* seed_d_w  = (const float*)d_in[4];
  const float* pool_wq_w = (const float*)d_in[5];
  const float* pool_wk_w = (const float*)d_in[6];
  const float* pool_wv_w = (const float*)d_in[7];
  const float* q_u_w     = (const float*)d_in[8];
  const float* q_g_w     = (const float*)d_in[9];
  const float* q_g_b     = (const float*)d_in[10];
  const float* kv_w      = (const float*)d_in[11];
  const float* mlp_w1    = (const float*)d_in[12];
  const float* mlp_b1    = (const float*)d_in[13];
  const float* mlp_w2    = (const float*)d_in[14];
  const float* mlp_b2    = (const float*)d_in[15];
  const float* ln_g      = (const float*)d_in[16];
  const float* ln_b      = (const float*)d_in[17];
  float* out = (float*)d_out;

  float* ws = (float*)d_ws;
  float* qvec  = ws;                 // B*DH
  float* qseed = ws + B * DH;        // B*DH
  float* utanA = ws + 2 * B * DH;    // B*DH
  float* utanB = ws + 3 * B * DH;    // B*DH
  float* parts = ws + 4 * B * DH;    // B*SPLITS*(DH+2)

  setup_pool_query<<<B, DH, 0, stream>>>(rho, seed_g_w, seed_g_b, pool_wq_w,
                                         pool_wk_w, qseed, qvec);
  attn_pass<<<B * SPLITS, 256, 0, stream>>>(demo, qvec, parts);
  trans_pool<<<B, DH, 0, stream>>>(parts, qseed, rho, pool_wv_w, seed_d_w,
                                   q_u_w, q_g_w, q_g_b, kv_w, ln_g, ln_b,
                                   utanA, qvec);
  attn_pass<<<B * SPLITS, 256, 0, stream>>>(demo, qvec, parts);
  trans_iter<<<B, DH, 0, stream>>>(parts, utanA, rho, kv_w, mlp_w1, mlp_b1,
                                   mlp_w2, mlp_b2, q_u_w, q_g_w, q_g_b, ln_g,
                                   ln_b, utanB, qvec, out, 0);
  attn_pass<<<B * SPLITS, 256, 0, stream>>>(demo, qvec, parts);
  trans_iter<<<B, DH, 0, stream>>>(parts, utanB, rho, kv_w, mlp_w1, mlp_b1,
                                   mlp_w2, mlp_b2, q_u_w, q_g_w, q_g_b, ln_g,
                                   ln_b, utanB, qvec, out, 1);
}

// Round 3
// 612.927 us; speedup vs baseline: 1.1244x; 1.1244x over previous
//
#include <hip/hip_runtime.h>
#include <cstddef>
#include <cstdint>

#define B 256
#define N 2048
#define DH 128
#define DG 256
#define HID 256
#define SPLITS 8
#define CHUNK (N / SPLITS)  // 256 rows per block
#define KITER (CHUNK / 16)  // 16: each block covers 16 rows per k-iter
#define SCALE 0.08838834764831845f
#define LN_EPS 1e-5f
#define TAN_NORM_MAX 6.2f  // artanh(1-1e-5)=6.103; safe upper bound

// ---------- helpers ----------

__device__ __forceinline__ float artanh_clip(float a) {
  a = fminf(a, 1.0f - 1e-5f);
  return 0.5f * __logf((1.0f + a) / (1.0f - a));
}

__device__ __forceinline__ float logmap_scale(float n2) {
  float nc = fmaxf(sqrtf(n2), 1e-7f);
  return artanh_clip(nc) / nc;
}

__device__ __forceinline__ float dotN(const float* __restrict__ wrow,
                                      const float* __restrict__ x, int n4) {
  const float4* a = (const float4*)wrow;
  const float4* bx = (const float4*)x;
  float s = 0.f;
  for (int j = 0; j < n4; ++j) {
    float4 u = a[j], v = bx[j];
    s += u.x * v.x + u.y * v.y + u.z * v.z + u.w * v.w;
  }
  return s;
}

// block reduction over 128 threads (2 waves)
__device__ __forceinline__ float blockSum128(float v, float* s_red) {
#pragma unroll
  for (int msk = 1; msk < 64; msk <<= 1) v += __shfl_xor(v, msk);
  if ((threadIdx.x & 63) == 0) s_red[threadIdx.x >> 6] = v;
  __syncthreads();
  float r = s_red[0] + s_red[1];
  __syncthreads();
  return r;
}

// merge SPLITS per-block partials (shared fixed max Mb => plain sums)
__device__ __forceinline__ float combine_partials(const float* __restrict__ partials,
                                                  int b, int tid) {
  const float* pb = partials + (size_t)b * SPLITS * (DH + 2);
  float L = 0.f, a = 0.f;
#pragma unroll
  for (int s = 0; s < SPLITS; ++s) {
    L += pb[s * (DH + 2) + DH];
    a += pb[s * (DH + 2) + tid];
  }
  return a / L;
}

// ---------- kernel 0: pooled-attention query  qvec = pool_wk_w^T (pool_wq_w (seed_g_w rho + b)) ----------

__global__ void setup_pool_query(const float* __restrict__ rho,
                                 const float* __restrict__ seed_g_w,
                                 const float* __restrict__ seed_g_b,
                                 const float* __restrict__ pool_wq_w,
                                 const float* __restrict__ pool_wk_w,
                                 float* __restrict__ q_seed,
                                 float* __restrict__ qvec,
                                 float* __restrict__ mb) {
  const int b = blockIdx.x, tid = threadIdx.x;
  __shared__ __align__(16) float s_rho[DG];
  __shared__ __align__(16) float s_qs[DH];
  __shared__ __align__(16) float s_qk[DH];
  __shared__ float s_red[2];
  s_rho[tid] = rho[b * DG + tid];
  s_rho[tid + DH] = rho[b * DG + tid + DH];
  __syncthreads();
  float qs = seed_g_b[tid] + dotN(seed_g_w + (size_t)tid * DG, s_rho, DG / 4);
  q_seed[b * DH + tid] = qs;
  s_qs[tid] = qs;
  __syncthreads();
  float qk = dotN(pool_wq_w + (size_t)tid * DH, s_qs, DH / 4);
  s_qk[tid] = qk;
  __syncthreads();
  float qp = 0.f;
  for (int i = 0; i < DH; ++i) qp += pool_wk_w[i * DH + tid] * s_qk[i];
  qvec[b * DH + tid] = qp;
  float qn2 = blockSum128(qp * qp, s_red);
  if (tid == 0) mb[b] = SCALE * TAN_NORM_MAX * sqrtf(qn2);
}

// ---------- attention pass ----------
// Fixed-bound softmax: Mb >= max score (Cauchy-Schwarz: |s| <= SCALE*|q|*artanh(1-1e-5)),
// so exp(s-Mb) never overflows and no running max / rescale chain is needed.
// Each wave handles 2 row-pairs per k-iter (4 rows, 2 float4 loads), prefetched one
// iteration ahead -> up to 4 loads in flight, no dependent-use-at-issue stall.

__global__ __launch_bounds__(256, 6) void attn_pass(const float* __restrict__ demo,
                                                    const float* __restrict__ qvec,
                                                    const float* __restrict__ mb,
                                                    float* __restrict__ partials) {
  const int blk = blockIdx.x;
  const int b = blk >> 3;       // SPLITS == 8
  const int s = blk & 7;
  const int tid = threadIdx.x;
  const int w = tid >> 6;       // wave id 0..3
  const int lane = tid & 63;
  const int il = lane & 31;
  const int half = lane >> 5;   // half-wave = one row

  const float4 qv = *(const float4*)(qvec + b * DH + ((lane * 4) & 127));
  const float Mb = mb[b];
  // wave w covers rows {k*16 + 2w, +1} (pair a) and {k*16 + 8 + 2w, +1} (pair b)
  const float* p0 = demo + ((size_t)b * N + (size_t)s * CHUNK + (size_t)(w * 2)) * DH + lane * 4;

  float la = 0.f, lb = 0.f;
  float4 aa = make_float4(0.f, 0.f, 0.f, 0.f);
  float4 ab = make_float4(0.f, 0.f, 0.f, 0.f);

  float4 xa = *(const float4*)(p0);
  float4 xb = *(const float4*)(p0 + 8 * DH);

  for (int k = 0; k < KITER; ++k) {
    float4 ca = xa, cb = xb;
    if (k + 1 < KITER) {
      const float* pn_ = p0 + (size_t)(k + 1) * 16 * DH;
      xa = *(const float4*)(pn_);
      xb = *(const float4*)(pn_ + 8 * DH);
    }
    // pair a
    {
      float n2 = ca.x * ca.x + ca.y * ca.y + ca.z * ca.z + ca.w * ca.w;
      float dd = qv.x * ca.x + qv.y * ca.y + qv.z * ca.z + qv.w * ca.w;
#pragma unroll
      for (int msk = 1; msk < 32; msk <<= 1) {
        n2 += __shfl_xor(n2, msk);
        dd += __shfl_xor(dd, msk);
      }
      float ts = logmap_scale(n2);
      float p = __expf(dd * ts * SCALE - Mb);
      la += p;
      float c = p * ts;
      aa.x += c * ca.x; aa.y += c * ca.y; aa.z += c * ca.z; aa.w += c * ca.w;
    }
    // pair b
    {
      float n2 = cb.x * cb.x + cb.y * cb.y + cb.z * cb.z + cb.w * cb.w;
      float dd = qv.x * cb.x + qv.y * cb.y + qv.z * cb.z + qv.w * cb.w;
#pragma unroll
      for (int msk = 1; msk < 32; msk <<= 1) {
        n2 += __shfl_xor(n2, msk);
        dd += __shfl_xor(dd, msk);
      }
      float ts = logmap_scale(n2);
      float p = __expf(dd * ts * SCALE - Mb);
      lb += p;
      float c = p * ts;
      ab.x += c * cb.x; ab.y += c * cb.y; ab.z += c * cb.z; ab.w += c * cb.w;
    }
  }

  float l = la + lb;
  float4 acc;
  acc.x = aa.x + ab.x; acc.y = aa.y + ab.y; acc.z = aa.z + ab.z; acc.w = aa.w + ab.w;
  // fold two half-waves (different rows, same d-slice)
  acc.x += __shfl_xor(acc.x, 32);
  acc.y += __shfl_xor(acc.y, 32);
  acc.z += __shfl_xor(acc.z, 32);
  acc.w += __shfl_xor(acc.w, 32);
  l += __shfl_xor(l, 32);

  __shared__ __align__(16) float s_acc[4][DH];
  __shared__ float s_l[4];
  if (half == 0) *(float4*)&s_acc[w][il * 4] = acc;
  if (lane == 0) s_l[w] = l;
  __syncthreads();
  if (tid < DH) {
    float a = s_acc[0][tid] + s_acc[1][tid] + s_acc[2][tid] + s_acc[3][tid];
    float* p = partials + (size_t)blk * (DH + 2);
    p[tid] = a;
    if (tid == 0) p[DH] = s_l[0] + s_l[1] + s_l[2] + s_l[3];
  }
}

// ---------- transition after pool pass ----------

__global__ void trans_pool(const float* __restrict__ partials,
                           const float* __restrict__ q_seed,
                           const float* __restrict__ rho,
                           const float* __restrict__ pool_wv_w,
                           const float* __restrict__ seed_d_w,
                           const float* __restrict__ q_u_w,
                           const float* __restrict__ q_g_w,
                           const float* __restrict__ q_g_b,
                           const float* __restrict__ kv_w,
                           const float* __restrict__ ln_g,
                           const float* __restrict__ ln_b,
                           float* __restrict__ u_tan_out,
                           float* __restrict__ qvec_out,
                           float* __restrict__ mb) {
  const int b = blockIdx.x, tid = threadIdx.x;
  __shared__ __align__(16) float s_a[DH];
  __shared__ __align__(16) float s_b[DH];
  __shared__ __align__(16) float s_rho[DG];
  __shared__ float s_red[2];

  float w0 = combine_partials(partials, b, tid);
  s_a[tid] = w0;
  s_rho[tid] = rho[b * DG + tid];
  s_rho[tid + DH] = rho[b * DG + tid + DH];
  __syncthreads();
  float pooled = dotN(pool_wv_w + (size_t)tid * DH, s_a, DH / 4);
  s_b[tid] = pooled;
  __syncthreads();
  float v = q_seed[b * DH + tid] + dotN(seed_d_w + (size_t)tid * DH, s_b, DH / 4);
  // expmap0
  float n2 = blockSum128(v * v, s_red);
  float nc = fmaxf(sqrtf(n2), 1e-7f);
  float u = v * (tanhf(nc) / nc);
  // logmap0
  float nu2 = blockSum128(u * u, s_red);
  float nuc = fmaxf(sqrtf(nu2), 1e-7f);
  float ut = u * (artanh_clip(nuc) / nuc);
  // LayerNorm (reference reassigns u_tan to the LN'd value)
  float mu = blockSum128(ut, s_red) * (1.0f / DH);
  float d = ut - mu;
  float var = blockSum128(d * d, s_red) * (1.0f / DH);
  float y = d * rsqrtf(var + LN_EPS) * ln_g[tid] + ln_b[tid];
  u_tan_out[b * DH + tid] = y;
  s_a[tid] = y;
  __syncthreads();
  float q = q_g_b[tid] + dotN(q_u_w + (size_t)tid * DH, s_a, DH / 4) +
            dotN(q_g_w + (size_t)tid * DG, s_rho, DG / 4);
  s_b[tid] = q;
  __syncthreads();
  float qp = 0.f;
  for (int i = 0; i < DH; ++i) qp += kv_w[i * DH + tid] * s_b[i];
  qvec_out[b * DH + tid] = qp;
  float qn2 = blockSum128(qp * qp, s_red);
  if (tid == 0) mb[b] = SCALE * TAN_NORM_MAX * sqrtf(qn2);
}

// ---------- loop-iteration transition ----------

__global__ void trans_iter(const float* __restrict__ partials,
                           const float* __restrict__ u_tan_in,
                           const float* __restrict__ rho,
                           const float* __restrict__ kv_w,
                           const float* __restrict__ mlp_w1,
                           const float* __restrict__ mlp_b1,
                           const float* __restrict__ mlp_w2,
                           const float* __restrict__ mlp_b2,
                           const float* __restrict__ q_u_w,
                           const float* __restrict__ q_g_w,
                           const float* __restrict__ q_g_b,
                           const float* __restrict__ ln_g,
                           const float* __restrict__ ln_b,
                           float* __restrict__ u_tan_out,
                           float* __restrict__ qvec_out,
                           float* __restrict__ mb,
                           float* __restrict__ out, int is_final) {
  const int b = blockIdx.x, tid = threadIdx.x;
  __shared__ __align__(16) float s_a[DH];
  __shared__ __align__(16) float s_b[DH];
  __shared__ __align__(16) float s_h[HID];
  __shared__ __align__(16) float s_rho[DG];
  __shared__ float s_red[2];

  float wv = combine_partials(partials, b, tid);
  s_a[tid] = wv;
  s_rho[tid] = rho[b * DG + tid];
  s_rho[tid + DH] = rho[b * DG + tid + DH];
  __syncthreads();
  float delta = dotN(kv_w + (size_t)tid * DH, s_a, DH / 4);
  s_b[tid] = delta;
  __syncthreads();
  float h0 = mlp_b1[tid] + dotN(mlp_w1 + (size_t)tid * DH, s_b, DH / 4);
  float h1 = mlp_b1[tid + DH] + dotN(mlp_w1 + (size_t)(tid + DH) * DH, s_b, DH / 4);
  s_h[tid] = 0.5f * h0 * (1.0f + erff(h0 * 0.70710678118654752f));
  s_h[tid + DH] = 0.5f * h1 * (1.0f + erff(h1 * 0.70710678118654752f));
  __syncthreads();
  float upd = mlp_b2[tid] + dotN(mlp_w2 + (size_t)tid * HID, s_h, HID / 4);
  float v = u_tan_in[b * DH + tid] + upd;
  // expmap0
  float n2 = blockSum128(v * v, s_red);
  float nc = fmaxf(sqrtf(n2), 1e-7f);
  float u = v * (tanhf(nc) / nc);
  if (is_final) {
    out[b * DH + tid] = u;
    return;
  }
  // logmap0
  float nu2 = blockSum128(u * u, s_red);
  float nuc = fmaxf(sqrtf(nu2), 1e-7f);
  float ut = u * (artanh_clip(nuc) / nuc);
  // LayerNorm (post-LN tangent feeds forward)
  float mu = blockSum128(ut, s_red) * (1.0f / DH);
  float d = ut - mu;
  float var = blockSum128(d * d, s_red) * (1.0f / DH);
  float y = d * rsqrtf(var + LN_EPS) * ln_g[tid] + ln_b[tid];
  u_tan_out[b * DH + tid] = y;
  s_a[tid] = y;
  __syncthreads();
  float q = q_g_b[tid] + dotN(q_u_w + (size_t)tid * DH, s_a, DH / 4) +
            dotN(q_g_w + (size_t)tid * DG, s_rho, DG / 4);
  s_b[tid] = q;
  __syncthreads();
  float qp = 0.f;
  for (int i = 0; i < DH; ++i) qp += kv_w[i * DH + tid] * s_b[i];
  qvec_out[b * DH + tid] = qp;
  float qn2 = blockSum128(qp * qp, s_red);
  if (tid == 0) mb[b] = SCALE * TAN_NORM_MAX * sqrtf(qn2);
}

// ---------- launch ----------

extern "C" void kernel_launch(void* const* d_in, const int* in_sizes, int n_in,
                              void* d_out, int out_size, void* d_ws, size_t ws_size,
                              hipStream_t stream) {
  const float* demo      = (const float*)d_in[0];
  const float* rho       = (const float*)d_in[1];
  const float* seed_g_w  = (const float*)d_in[2];
  const float* seed_g_b  = (const float*)d_in[3];
  const float* seed_d_w  = (const float*)d_in[4];
  const float* pool_wq_w = (const float*)d_in[5];
  const float* pool_wk_w = (const float*)d_in[6];
  const float* pool_wv_w = (const float*)d_in[7];
  const float* q_u_w     = (const float*)d_in[8];
  const float* q_g_w     = (const float*)d_in[9];
  const float* q_g_b     = (const float*)d_in[10];
  const float* kv_w      = (const float*)d_in[11];
  const float* mlp_w1    = (const float*)d_in[12];
  const float* mlp_b1    = (const float*)d_in[13];
  const float* mlp_w2    = (const float*)d_in[14];
  const float* mlp_b2    = (const float*)d_in[15];
  const float* ln_g      = (const float*)d_in[16];
  const float* ln_b      = (const float*)d_in[17];
  float* out = (float*)d_out;

  float* ws = (float*)d_ws;
  float* qvec  = ws;                 // B*DH
  float* qseed = ws + B * DH;        // B*DH
  float* utanA = ws + 2 * B * DH;    // B*DH
  float* utanB = ws + 3 * B * DH;    // B*DH
  float* mb    = ws + 4 * B * DH;    // B
  float* parts = ws + 4 * B * DH + B;  // B*SPLITS*(DH+2)

  setup_pool_query<<<B, DH, 0, stream>>>(rho, seed_g_w, seed_g_b, pool_wq_w,
                                         pool_wk_w, qseed, qvec, mb);
  attn_pass<<<B * SPLITS, 256, 0, stream>>>(demo, qvec, mb, parts);
  trans_pool<<<B, DH, 0, stream>>>(parts, qseed, rho, pool_wv_w, seed_d_w,
                                   q_u_w, q_g_w, q_g_b, kv_w, ln_g, ln_b,
                                   utanA, qvec, mb);
  attn_pass<<<B * SPLITS, 256, 0, stream>>>(demo, qvec, mb, parts);
  trans_iter<<<B, DH, 0, stream>>>(parts, utanA, rho, kv_w, mlp_w1, mlp_b1,
                                   mlp_w2, mlp_b2, q_u_w, q_g_w, q_g_b, ln_g,
                                   ln_b, utanB, qvec, mb, out, 0);
  attn_pass<<<B * SPLITS, 256, 0, stream>>>(demo, qvec, mb, parts);
  trans_iter<<<B, DH, 0, stream>>>(parts, utanB, rho, kv_w, mlp_w1, mlp_b1,
                                   mlp_w2, mlp_b2, q_u_w, q_g_w, q_g_b, ln_g,
                                   ln_b, utanB, qvec, mb, out, 1);
}